// Round 2
// baseline (134.817 us; speedup 1.0000x reference)
//
#include <hip/hip_runtime.h>
#include <hip/hip_bf16.h>
#include <cstdint>

#define BATCH   32
#define NVARS   16
#define SAMPLES 4096
#define EDIM    128
#define NTOK    1016          // (4096-32)/4

typedef __bf16 bf8_t __attribute__((ext_vector_type(8)));
typedef float  f4_t  __attribute__((ext_vector_type(4)));

// ---------------------------------------------------------------------------
// prep_kernel: W_patch repack ONLY (encode fused into the GEMM).
// WtF[kb][g(8)][lane(64)][t(8)] = B[kbase(kb)+quad*8+t][g*16+l15]
//   (kbase=(4*dlt+(s&3))*128+(s>>2)*32, kb=s*8+dlt) -> a GEMM wave's
//   B-fragment group is one coalesced 1KB global load straight to VGPRs.
// ---------------------------------------------------------------------------
__global__ __launch_bounds__(256) void prep_kernel(
    const float* __restrict__ Wp, __hip_bfloat16* __restrict__ WtF)
{
  __shared__ float ls[32][132];
  int tid = threadIdx.x;
  int kb  = blockIdx.x;
  int s = kb >> 3, dlt = kb & 7;
  int kbase = (4 * dlt + (s & 3)) * 128 + (s >> 2) * 32;
#pragma unroll
  for (int r = 0; r < 16; ++r) {
    int idx = tid + r * 256;
    ls[idx >> 7][idx & 127] =
        Wp[(size_t)(kbase + (idx >> 7)) * EDIM + (idx & 127)];
  }
  __syncthreads();
  int g = tid >> 5, l5 = tid & 31;
#pragma unroll
  for (int h = 0; h < 2; ++h) {
    int lane = l5 + h * 32;
    int quad = lane >> 4, l15 = lane & 15;
    int n = g * 16 + l15;
    union { unsigned short u[8]; uint4 v; } pk;
#pragma unroll
    for (int t = 0; t < 8; ++t) {
      __hip_bfloat16 hh = __float2bfloat16(ls[quad * 8 + t][n]);
      pk.u[t] = *(unsigned short*)&hh;
    }
    *(uint4*)(WtF + (size_t)kb * 4096 + g * 512 + lane * 8) = pk.v;
  }
}

// ---------------------------------------------------------------------------
// Fused GEMM + in-kernel encode, R2: broadcast-read encode.
//
// R1 post-mortem: per-lane full-row xT reads (4x b128, unique addrs) made
// encode LDS traffic 1280 b128/CU (~16 us serialized against the compute
// path's A-fragment reads) -> gemm 62.5 us, MfmaUtil 21%.
//
// R2 encode structure: one row per 16-lane group (broadcast ds_read_b128,
// ~free), lane l15 computes dims {2*l15, 2*l15+1} of the 32-dim e-block.
// Per wave-unit: 4 rows (quads), rows r = u*16 + wq*4 + quad; 8 units +
// tail unit (rows 128..135, waves wq<2, wave-uniform -> no divergence).
// Both e-half W columns held in regs (w0/w1, [16][2] each) -> no reload.
// Write: ds_write_b32 at phys=((l15>>2)+(r>>1))&3 slot (t0 = 0 mod 128 so
// (t0+r)>>1 = r>>1 mod 4); matches compute's swzA=(quad+((t0+row)>>1))&3
// since the i*16 row term is 0 mod 4 after >>1.  Write bank pattern: rows
// r,r+2 alias -> 2-way, free (m136).  Summation v-ascending f32 ->
// bit-identical enc vs R0 prep.
// xT[4][136][20] f32: pitch-20 rows; group reads at quad*80B -> banks
// {0,20,8,28}+4j mod 32, disjoint -> conflict-free broadcast.
// ---------------------------------------------------------------------------
__global__ __launch_bounds__(512, 2) void gemm_kernel(
    const float* __restrict__ x,
    const float* __restrict__ Ws,
    const float* __restrict__ bs,
    const __hip_bfloat16* __restrict__ WtF,
    const float* __restrict__ bp,
    float* __restrict__ out)
{
  __shared__ __align__(16) __hip_bfloat16 Apl[2][2][4608];  // 36 KB
  __shared__ __align__(16) float xT[4][136][20];            // 42.5 KB

  int tid  = threadIdx.x;
  int lane = tid & 63;
  int wv   = tid >> 6;               // 0..7
  int g    = wv >> 2;                // K-half
  int wq   = wv & 3;                 // quadrant of 128x128
  int b    = blockIdx.x >> 3;
  int t0   = (blockIdx.x & 7) << 7;
  int wm   = (wq >> 1) << 6;         // 0/64
  int wn   = (wq & 1) << 6;          // 0/64
  int quad = lane >> 4;
  int l15  = lane & 15;

  const __hip_bfloat16* bg = WtF + (size_t)(wn >> 4) * 512 + lane * 8;

  f4_t acc[4][4];
  f4_t zero = {0.f, 0.f, 0.f, 0.f};
#pragma unroll
  for (int i = 0; i < 4; ++i)
#pragma unroll
    for (int j = 0; j < 4; ++j) acc[i][j] = zero;

  // ---- W_sample columns for this lane's 2 dims, both e-halves ----
  float w0[NVARS][2], w1[NVARS][2];
  float bz0[2], bz1[2];
  {
    int dA = (g * 2) * 32 + 2 * l15;
    int dB = dA + 32;
#pragma unroll
    for (int v = 0; v < NVARS; ++v) {
      float2 ta = *(const float2*)(Ws + v * EDIM + dA);
      float2 tb = *(const float2*)(Ws + v * EDIM + dB);
      w0[v][0] = ta.x; w0[v][1] = ta.y;
      w1[v][0] = tb.x; w1[v][1] = tb.y;
    }
    float2 ba = *(const float2*)(bs + dA);
    float2 bb = *(const float2*)(bs + dB);
    bz0[0] = ba.x; bz0[1] = ba.y;
    bz1[0] = bb.x; bz1[1] = bb.y;
  }

  // ---- stage x[b][v][4t0 .. 4t0+543] transposed into xT (clamped) ----
  {
    int v = tid >> 5, l5 = tid & 31;
    const float* xb = x + ((size_t)b * NVARS + v) * SAMPLES;
    int sb = t0 << 2;
#pragma unroll
    for (int j = 0; j < 17; ++j) {
      int i = l5 + j * 32;           // 0..543
      int s = sb + i; s = s > (SAMPLES - 1) ? (SAMPLES - 1) : s;
      xT[i & 3][i >> 2][v] = xb[s];
    }
  }

  int rbase = wq * 4 + quad;         // 0..15 within a 16-row unit
  int wrbyte = (l15 & 3) * 4;        // dword slot within phys chunk

  // one row-encode: group-broadcast read, 2 dims, packed b32 write
  auto encRow = [&](const float* xp, __hip_bfloat16* dstbuf, int r,
                    const float (*w)[2], const float* bz) {
    const float* xrow = xp + r * 20;
    float xr[NVARS];
    *(float4*)&xr[0]  = *(const float4*)(xrow + 0);
    *(float4*)&xr[4]  = *(const float4*)(xrow + 4);
    *(float4*)&xr[8]  = *(const float4*)(xrow + 8);
    *(float4*)&xr[12] = *(const float4*)(xrow + 12);
    float a0 = bz[0], a1 = bz[1];
#pragma unroll
    for (int v = 0; v < NVARS; ++v) {
      a0 += xr[v] * w[v][0];
      a1 += xr[v] * w[v][1];
    }
    unsigned u0 = __float_as_uint(floorf(a0));
    unsigned u1 = __float_as_uint(floorf(a1));
    unsigned pk = (u0 >> 16) | (u1 & 0xffff0000u);
    int phys = ((l15 >> 2) + (r >> 1)) & 3;    // t0 contributes 0 mod 4
    *(unsigned*)((char*)dstbuf + r * 64 + phys * 16 + wrbyte) = pk;
  };

  auto loadB = [&](int kb, uint4* d) {
#pragma unroll
    for (int j = 0; j < 4; ++j)
      d[j] = *(const uint4*)(bg + (size_t)kb * 4096 + j * 512);
  };

  auto compute = [&](int abuf, int dlt, const uint4* bq_) {
    const bf8_t* pA = (const bf8_t*)&Apl[g][abuf][0];
    int swzA = (quad + ((t0 + dlt + wm + l15) >> 1)) & 3;
    bf8_t af[4];
#pragma unroll
    for (int i = 0; i < 4; ++i)
      af[i] = pA[(dlt + wm + i * 16 + l15) * 4 + swzA];
    __builtin_amdgcn_s_setprio(1);
#pragma unroll
    for (int mi = 0; mi < 4; ++mi)
#pragma unroll
      for (int ni = 0; ni < 4; ++ni)
        acc[mi][ni] = __builtin_amdgcn_mfma_f32_16x16x32_bf16(
            af[mi], __builtin_bit_cast(bf8_t, bq_[ni]), acc[mi][ni], 0, 0, 0);
    __builtin_amdgcn_s_setprio(0);
  };

  // ---- prologue: xT ready, encode plane 0 (p=0, e-half 0) into buf 0 ----
  __syncthreads();
  {
    const float* xp = &xT[0][0][0];
    __hip_bfloat16* dst = &Apl[g][0][0];
#pragma unroll
    for (int u = 0; u < 8; ++u) encRow(xp, dst, u * 16 + rbase, w0, bz0);
    if (wq < 2) encRow(xp, dst, 128 + rbase, w0, bz0);
  }
  asm volatile("s_waitcnt lgkmcnt(0)" ::: "memory");
  asm volatile("s_barrier" ::: "memory");

  uint4 bq[2][4];
  loadB(g * 64, bq[0]);
  loadB(g * 64 + 1, bq[1]);

  for (int ss = 0; ss < 8; ++ss) {           // group-local supersteps
    int sn = ss + 1;                         // plane to encode this ss
    const float* xp = &xT[sn & 3][0][0];
    __hip_bfloat16* dst = &Apl[g][sn & 1][0];
    const float (*wp)[2] = (sn >> 2) ? w1 : w0;
    const float* bzp     = (sn >> 2) ? bz1 : bz0;
#pragma unroll
    for (int d = 0; d < 8; ++d) {
      int kl = ss * 8 + d;                   // group-local kb 0..63
      compute(ss & 1, d, bq[d & 1]);
      if (kl < 62) loadB(g * 64 + kl + 2, bq[d & 1]);
      if (ss < 7) {
        encRow(xp, dst, d * 16 + rbase, wp, bzp);
        if (d == 7 && wq < 2) encRow(xp, dst, 128 + rbase, wp, bzp);
      }
    }
    asm volatile("s_waitcnt lgkmcnt(0)" ::: "memory");
    asm volatile("s_barrier" ::: "memory");
  }

  // ---- K-half reduction (group1 -> group0 via LDS) + fused epilogue ----
  // stride-17 float rows: 17 coprime to 32 -> conflict-free LDS access.
  float* rb = (float*)&Apl[0][0][0];         // 4352 floats = 17 KB per round
  int widx = (wq * 64 + lane) * 17;
  float bias[4];
#pragma unroll
  for (int ni = 0; ni < 4; ++ni) bias[ni] = bp[wn + ni * 16 + l15];

#pragma unroll
  for (int mi = 0; mi < 4; ++mi) {
    __syncthreads();
    if (g == 1) {
#pragma unroll
      for (int ni = 0; ni < 4; ++ni)
#pragma unroll
        for (int r = 0; r < 4; ++r)
          rb[widx + ni * 4 + r] = acc[mi][ni][r];
    }
    __syncthreads();
    if (g == 0) {
#pragma unroll
      for (int ni = 0; ni < 4; ++ni)
#pragma unroll
        for (int r = 0; r < 4; ++r) {
          int t = t0 + wm + mi * 16 + quad * 4 + r;
          if (t < NTOK) {
            int n = wn + ni * 16 + l15;
            out[((size_t)b * NTOK + t) * EDIM + n] =
                floorf(acc[mi][ni][r] + rb[widx + ni * 4 + r] + bias[ni]);
          }
        }
    }
  }
}

// ---------------------------------------------------------------------------
extern "C" void kernel_launch(void* const* d_in, const int* in_sizes, int n_in,
                              void* d_out, int out_size, void* d_ws, size_t ws_size,
                              hipStream_t stream) {
  const float* x  = (const float*)d_in[0];
  const float* Ws = (const float*)d_in[1];
  const float* bs = (const float*)d_in[2];
  const float* Wp = (const float*)d_in[3];
  const float* bp = (const float*)d_in[4];
  float* out = (float*)d_out;

  __hip_bfloat16* WtF = (__hip_bfloat16*)d_ws;   // 1 MB fragment-major B

  prep_kernel<<<128, 256, 0, stream>>>(Wp, WtF);
  gemm_kernel<<<BATCH * 8, 512, 0, stream>>>(x, Ws, bs, WtF, bp, out);
}

// Round 3
// 106.741 us; speedup vs baseline: 1.2630x; 1.2630x over previous
//
#include <hip/hip_runtime.h>
#include <hip/hip_bf16.h>
#include <cstdint>

#define BATCH   32
#define NVARS   16
#define SAMPLES 4096
#define EDIM    128
#define NTOK    1016          // (4096-32)/4
#define PLELEM  4368          // bf16 per plane slot = 8736 B (16B-aligned; 8736/4 mod 32 = 8 -> per-plane bank stagger)

typedef __bf16 bf8_t __attribute__((ext_vector_type(8)));
typedef float  f4_t  __attribute__((ext_vector_type(4)));

// ---------------------------------------------------------------------------
// prep_kernel: W_patch repack ONLY.
// WtF[kb][g(8)][lane(64)][t(8)] = B[kbase(kb)+quad*8+t][g*16+l15]
//   (kbase=(4*dlt+(s&3))*128+(s>>2)*32, kb=s*8+dlt) -> a GEMM wave's
//   B-fragment group is one coalesced 1KB global load straight to VGPRs.
// ---------------------------------------------------------------------------
__global__ __launch_bounds__(256) void prep_kernel(
    const float* __restrict__ Wp, __hip_bfloat16* __restrict__ WtF)
{
  __shared__ float ls[32][132];
  int tid = threadIdx.x;
  int kb  = blockIdx.x;
  int s = kb >> 3, dlt = kb & 7;
  int kbase = (4 * dlt + (s & 3)) * 128 + (s >> 2) * 32;
#pragma unroll
  for (int r = 0; r < 16; ++r) {
    int idx = tid + r * 256;
    ls[idx >> 7][idx & 127] =
        Wp[(size_t)(kbase + (idx >> 7)) * EDIM + (idx & 127)];
  }
  __syncthreads();
  int g = tid >> 5, l5 = tid & 31;
#pragma unroll
  for (int h = 0; h < 2; ++h) {
    int lane = l5 + h * 32;
    int quad = lane >> 4, l15 = lane & 15;
    int n = g * 16 + l15;
    union { unsigned short u[8]; uint4 v; } pk;
#pragma unroll
    for (int t = 0; t < 8; ++t) {
      __hip_bfloat16 hh = __float2bfloat16(ls[quad * 8 + t][n]);
      pk.u[t] = *(unsigned short*)&hh;
    }
    *(uint4*)(WtF + (size_t)kb * 4096 + g * 512 + lane * 8) = pk.v;
  }
}

// ---------------------------------------------------------------------------
// R3: phase-split fusion. Whole A-panel (16 planes x 8736 B = 139.8 KB)
// resident in LDS; encode runs ONCE up front, then the GEMM main loop has
// ZERO barriers and ZERO staging (R1/R2 post-mortem: per-ss encode cost =
// LDS instruction count + 9x barrier-lockstep drain; both eliminated here).
// 1 block/CU (LDS 157.2 KB), 8 waves; VGPR budget 256 -> no pressure.
//
// Encode: x loaded to REGS as float4 (4 consecutive samples = all 4 phases
// of one row) -- one global load serves every plane.  Per phase p: ds_write
// the phase's column into ping-pong xTp (pitch 16 floats: a wave reads 2
// rows 64 B apart -> banks {16r, 16r+16}: disjoint, broadcast within 16
// lanes), then 8.5 tasks/thread: task = (row r, dim-quad q4=tid&31); thread's
// dims FIXED across phases (512 = 0 mod 32) -> w[16][4] = 64 VGPR, no
// reload.  Summation v-ascending f32 -> bit-identical enc values.
// Plane store [e][p] at stride PLELEM; write slot phys=(cq+(r>>1))&3
// matches compute's swzA=(quad+((t0+row)>>1))&3 (t0 = 0 mod 128; i*16 term
// = 0 mod 4 after >>1) -- same proven R0 swizzle math.
//
// GEMM: group-local ss 0..7 -> plane pl=(g*2+(ss>>2))*4+(ss&3); kb identity
// kl=ss*8+d <-> WtF kb=g*64+kl unchanged -> bit-identical K-order vs R0.
// Depth-2 B prefetch in VGPRs; af b128 reads; 16 MFMA per d with setprio.
// ---------------------------------------------------------------------------
__global__ __launch_bounds__(512, 1) void fused_kernel(
    const float* __restrict__ x,
    const float* __restrict__ Ws,
    const float* __restrict__ bs,
    const __hip_bfloat16* __restrict__ WtF,
    const float* __restrict__ bp,
    float* __restrict__ out)
{
  __shared__ __align__(16) __hip_bfloat16 Apan[16 * PLELEM];  // 139,776 B
  __shared__ __align__(16) float xTp[2][136][16];             //  17,408 B

  int tid  = threadIdx.x;
  int lane = tid & 63;
  int wv   = tid >> 6;               // 0..7
  int g    = wv >> 2;                // K-half
  int wq   = wv & 3;                 // quadrant of 128x128
  int b    = blockIdx.x >> 3;
  int t0   = (blockIdx.x & 7) << 7;
  int wm   = (wq >> 1) << 6;         // 0/64
  int wn   = (wq & 1) << 6;          // 0/64
  int quad = lane >> 4;
  int l15  = lane & 15;

  const __hip_bfloat16* bg = WtF + (size_t)(wn >> 4) * 512 + lane * 8;

  // ---------------- encode setup: fixed dim-quad per thread --------------
  int q4 = tid & 31;                 // dims 4*q4 .. 4*q4+3
  int eq = q4 >> 3;                  // e-block 0..3
  int cq = (q4 >> 1) & 3;            // 16B chunk within row
  int hq = q4 & 1;                   // 8B half within chunk
  int r0 = tid >> 5;                 // 0..15 (row base, +16j)

  float w[NVARS][4];
  float bz[4];
  {
    int d0 = q4 * 4;
#pragma unroll
    for (int v = 0; v < NVARS; ++v)
      *(float4*)&w[v][0] = *(const float4*)(Ws + v * EDIM + d0);
    *(float4*)&bz[0] = *(const float4*)(bs + d0);
  }

  // ---------------- x -> regs: (row, var), float4 = 4 phases -------------
  int vv = tid & 15, rr = tid >> 4;  // rr 0..31
  float4 xreg[5];
  {
    const float* xb = x + ((size_t)b * NVARS + vv) * SAMPLES;
#pragma unroll
    for (int j = 0; j < 4; ++j) {
      int s4 = (t0 + rr + 32 * j) * 4;           // max 4092: in bounds
      xreg[j] = *(const float4*)(xb + s4);
    }
    if (tid < 128) {                             // rows 128..135 (rr<8)
      int s4 = (t0 + 128 + rr) * 4;
      if (s4 > SAMPLES - 4) s4 = SAMPLES - 4;    // clamp (masked tokens only)
      xreg[4] = *(const float4*)(xb + s4);
    }
  }

  // ---------------- phase staging + encode -------------------------------
  auto stageX = [&](int p, int buf) {
#pragma unroll
    for (int j = 0; j < 4; ++j) {
      float c = (p == 0) ? xreg[j].x : (p == 1) ? xreg[j].y
              : (p == 2) ? xreg[j].z : xreg[j].w;
      xTp[buf][rr + 32 * j][vv] = c;
    }
    if (tid < 128) {
      float c = (p == 0) ? xreg[4].x : (p == 1) ? xreg[4].y
              : (p == 2) ? xreg[4].z : xreg[4].w;
      xTp[buf][128 + rr][vv] = c;
    }
  };

  auto encTask = [&](int p, int buf, int r) {
    const float* xr = &xTp[buf][r][0];
    float xv[NVARS];
    *(float4*)&xv[0]  = *(const float4*)(xr + 0);
    *(float4*)&xv[4]  = *(const float4*)(xr + 4);
    *(float4*)&xv[8]  = *(const float4*)(xr + 8);
    *(float4*)&xv[12] = *(const float4*)(xr + 12);
    float a0 = bz[0], a1 = bz[1], a2 = bz[2], a3 = bz[3];
#pragma unroll
    for (int v = 0; v < NVARS; ++v) {
      a0 += xv[v] * w[v][0]; a1 += xv[v] * w[v][1];
      a2 += xv[v] * w[v][2]; a3 += xv[v] * w[v][3];
    }
    union { unsigned short us[4]; uint2 q; } pk;
    pk.us[0] = (unsigned short)(__float_as_uint(floorf(a0)) >> 16);
    pk.us[1] = (unsigned short)(__float_as_uint(floorf(a1)) >> 16);
    pk.us[2] = (unsigned short)(__float_as_uint(floorf(a2)) >> 16);
    pk.us[3] = (unsigned short)(__float_as_uint(floorf(a3)) >> 16);
    int phys = (cq + (r >> 1)) & 3;              // t0 contributes 0 mod 4
    char* plbase = (char*)&Apan[(eq * 4 + p) * PLELEM];
    *(uint2*)(plbase + r * 64 + phys * 16 + hq * 8) = pk.q;
  };

  stageX(0, 0);
  __syncthreads();
#pragma unroll
  for (int p = 0; p < 4; ++p) {
    if (p < 3) stageX(p + 1, (p + 1) & 1);
    int buf = p & 1;
#pragma unroll
    for (int j = 0; j < 8; ++j) encTask(p, buf, r0 + 16 * j);
    if (tid < 256) encTask(p, buf, 128 + (tid >> 5));
    __syncthreads();
  }
  // panel fully resident; no further A traffic, no more barriers until epilogue

  // ---------------- GEMM main loop (barrier-free) ------------------------
  f4_t acc[4][4];
  f4_t zero = {0.f, 0.f, 0.f, 0.f};
#pragma unroll
  for (int i = 0; i < 4; ++i)
#pragma unroll
    for (int j = 0; j < 4; ++j) acc[i][j] = zero;

  auto loadB = [&](int kb, uint4* d) {
#pragma unroll
    for (int j = 0; j < 4; ++j)
      d[j] = *(const uint4*)(bg + (size_t)kb * 4096 + j * 512);
  };

  auto compute = [&](const bf8_t* pA, int dlt, const uint4* bq_) {
    int swzA = (quad + ((t0 + dlt + wm + l15) >> 1)) & 3;
    bf8_t af[4];
#pragma unroll
    for (int i = 0; i < 4; ++i)
      af[i] = pA[(dlt + wm + i * 16 + l15) * 4 + swzA];
    __builtin_amdgcn_s_setprio(1);
#pragma unroll
    for (int mi = 0; mi < 4; ++mi)
#pragma unroll
      for (int ni = 0; ni < 4; ++ni)
        acc[mi][ni] = __builtin_amdgcn_mfma_f32_16x16x32_bf16(
            af[mi], __builtin_bit_cast(bf8_t, bq_[ni]), acc[mi][ni], 0, 0, 0);
    __builtin_amdgcn_s_setprio(0);
  };

  uint4 bq[2][4];
  loadB(g * 64, bq[0]);
  loadB(g * 64 + 1, bq[1]);

  for (int ss = 0; ss < 8; ++ss) {
    int pl = (g * 2 + (ss >> 2)) * 4 + (ss & 3);
    const bf8_t* pA = (const bf8_t*)&Apan[pl * PLELEM];
#pragma unroll
    for (int d = 0; d < 8; ++d) {
      int kl = ss * 8 + d;                       // group-local kb 0..63
      compute(pA, d, bq[d & 1]);
      if (kl < 62) loadB(g * 64 + kl + 2, bq[d & 1]);
    }
  }

  // ---- K-half reduction (group1 -> group0 via LDS) + fused epilogue ----
  // stride-17 float rows: 17 coprime to 32 -> conflict-free LDS access.
  float* rb = (float*)&Apan[0];                  // 17.4 KB reuse of panel
  int widx = (wq * 64 + lane) * 17;
  float bias[4];
#pragma unroll
  for (int ni = 0; ni < 4; ++ni) bias[ni] = bp[wn + ni * 16 + l15];

#pragma unroll
  for (int mi = 0; mi < 4; ++mi) {
    __syncthreads();
    if (g == 1) {
#pragma unroll
      for (int ni = 0; ni < 4; ++ni)
#pragma unroll
        for (int r = 0; r < 4; ++r)
          rb[widx + ni * 4 + r] = acc[mi][ni][r];
    }
    __syncthreads();
    if (g == 0) {
#pragma unroll
      for (int ni = 0; ni < 4; ++ni)
#pragma unroll
        for (int r = 0; r < 4; ++r) {
          int t = t0 + wm + mi * 16 + quad * 4 + r;
          if (t < NTOK) {
            int n = wn + ni * 16 + l15;
            out[((size_t)b * NTOK + t) * EDIM + n] =
                floorf(acc[mi][ni][r] + rb[widx + ni * 4 + r] + bias[ni]);
          }
        }
    }
  }
}

// ---------------------------------------------------------------------------
extern "C" void kernel_launch(void* const* d_in, const int* in_sizes, int n_in,
                              void* d_out, int out_size, void* d_ws, size_t ws_size,
                              hipStream_t stream) {
  const float* x  = (const float*)d_in[0];
  const float* Ws = (const float*)d_in[1];
  const float* bs = (const float*)d_in[2];
  const float* Wp = (const float*)d_in[3];
  const float* bp = (const float*)d_in[4];
  float* out = (float*)d_out;

  __hip_bfloat16* WtF = (__hip_bfloat16*)d_ws;   // 1 MB fragment-major B

  prep_kernel<<<128, 256, 0, stream>>>(Wp, WtF);
  fused_kernel<<<BATCH * 8, 512, 0, stream>>>(x, Ws, bs, WtF, bp, out);
}